// Round 1
// 210.241 us; speedup vs baseline: 1.0178x; 1.0178x over previous
//
#include <hip/hip_runtime.h>
#include <math.h>

// Problem constants (fixed by setup_inputs)
constexpr int HOPS  = 3;
constexpr int VOCAB = 50257;
constexpr int DIM   = 128;
constexpr int NB    = 32;         // batch
constexpr int NM    = 512;        // story slots
constexpr int NS    = 6;          // tokens per story slot
constexpr int NT    = 128;        // trees
constexpr int NL    = 64;         // tokens per tree
constexpr int SLOTS = NM + NT;    // 640
constexpr size_t TS = (size_t)VOCAB * DIM;              // fp32 table stride in C
constexpr size_t TABSTRIDE = (size_t)NB * SLOTS * DIM;  // msum per-table stride (fp16 elems)

// fp16 compressed tables, token-interleaved: Ch[v][tab][d], tab 0..2 = C[1..3].
constexpr size_t CH_ELEMS = (size_t)VOCAB * 3 * DIM;    // 19,298,688
constexpr int NE8 = (int)(CH_ELEMS / 8);                // 2,412,336 half8 groups

typedef _Float16 half8 __attribute__((ext_vector_type(8)));
typedef _Float16 half4 __attribute__((ext_vector_type(4)));

constexpr int CONV_BLOCKS   = 2048;   // pure streaming converter
constexpr int GATHER_BLOCKS = 2048;   // 2 trees + 8 story slots per block

// ---------------------------------------------------------------------------
// Kernel 1: pure fp32 -> fp16 conversion, C[1..3] -> Ch interleaved [V][3][128].
// Fully coalesced stream: 77 MB read + 39 MB write, HBM-bound (~18 us target).
// ---------------------------------------------------------------------------
__global__ __launch_bounds__(256) void convert_k(
    const float* __restrict__ C, _Float16* __restrict__ Ch)
{
    for (int e8 = blockIdx.x * 256 + threadIdx.x; e8 < NE8; e8 += CONV_BLOCKS * 256) {
        const size_t base = (size_t)e8 * 8;
        const size_t v    = base / 384;
        const int    rem  = (int)(base % 384);
        const int    tab  = rem >> 7;             // 0..2
        const int    d    = rem & 127;            // 8-aligned
        const float* src = C + (size_t)(1 + tab) * TS + v * DIM + d;
        float4 f0 = *(const float4*)(src);
        float4 f1 = *(const float4*)(src + 4);
        half8 h;
        h[0]=(_Float16)f0.x; h[1]=(_Float16)f0.y; h[2]=(_Float16)f0.z; h[3]=(_Float16)f0.w;
        h[4]=(_Float16)f1.x; h[5]=(_Float16)f1.y; h[6]=(_Float16)f1.z; h[7]=(_Float16)f1.w;
        *(half8*)(Ch + base) = h;
    }
}

// ---------------------------------------------------------------------------
// Kernel 2: all gathers from fp16 Ch (L3-resident, 768 B/token for all 3 tables).
//  waves 0..1: one tree per wave. 4 quarters x 16 tokens; lane l16 owns dims
//              [l16*8, l16*8+8); cross-quarter shfl-xor reduce; quarter 0 writes.
//  waves 2..3: 4 story slots per wave, one slot per 16-lane quarter (6 tokens,
//              no cross-lane reduce). Story rows now cost 2 cache lines (fp16)
//              instead of 4 (fp32) -> half the MSHR occupancy per row.
// ---------------------------------------------------------------------------
__global__ __launch_bounds__(256) void gather_k(
    const _Float16* __restrict__ Ch, const int* __restrict__ story,
    const int* __restrict__ kb, _Float16* __restrict__ msum)
{
    const int wave = threadIdx.x >> 6, lane = threadIdx.x & 63;
    const int q = lane >> 4, l16 = lane & 15;

    if (wave < 2) {
        // ---- tree gather: g = b*NT + tree in [0, 4096) ----
        const int g = blockIdx.x * 2 + wave;
        const int b = g >> 7, tr = g & (NT - 1);

        const int tok = kb[(size_t)g * NL + lane];    // coalesced 64-token load

        float a0[8] = {0,0,0,0,0,0,0,0};
        float a1[8] = {0,0,0,0,0,0,0,0};
        float a2[8] = {0,0,0,0,0,0,0,0};

        #pragma unroll
        for (int i = 0; i < 16; ++i) {
            const int s = __shfl(tok, (lane & 48) + i);   // token q*16+i of my tree
            const _Float16* p = Ch + (size_t)s * (3 * DIM) + l16 * 8;
            half8 v0 = *(const half8*)(p);
            half8 v1 = *(const half8*)(p + DIM);
            half8 v2 = *(const half8*)(p + 2 * DIM);
            #pragma unroll
            for (int j = 0; j < 8; ++j) {
                a0[j] = fmaf((float)v0[j], 1.0f, a0[j]);
                a1[j] = fmaf((float)v1[j], 1.0f, a1[j]);
                a2[j] = fmaf((float)v2[j], 1.0f, a2[j]);
            }
        }
        // reduce the 4 quarter-partials (lanes differ only in q bits 4..5)
        #pragma unroll
        for (int j = 0; j < 8; ++j) {
            a0[j] += __shfl_xor(a0[j], 16); a0[j] += __shfl_xor(a0[j], 32);
            a1[j] += __shfl_xor(a1[j], 16); a1[j] += __shfl_xor(a1[j], 32);
            a2[j] += __shfl_xor(a2[j], 16); a2[j] += __shfl_xor(a2[j], 32);
        }
        if (q == 0) {
            half8 h0, h1, h2;
            #pragma unroll
            for (int j = 0; j < 8; ++j) {
                h0[j] = (_Float16)a0[j]; h1[j] = (_Float16)a1[j]; h2[j] = (_Float16)a2[j];
            }
            const size_t o = ((size_t)b * SLOTS + NM + tr) * DIM + l16 * 8;
            *(half8*)(msum + o)                 = h0;
            *(half8*)(msum + o + TABSTRIDE)     = h1;
            *(half8*)(msum + o + 2 * TABSTRIDE) = h2;
        }
    } else {
        // ---- story gather: 8 slots per block, 4 per wave, 1 per quarter ----
        const int wbase = blockIdx.x * 8 + (wave - 2) * 4;   // first slot of wave
        const int* sidx = story + (size_t)wbase * NS;
        const int tokv = (lane < 4 * NS) ? sidx[lane] : 0;   // 24 coalesced ints

        const int g = wbase + q;                  // b*NM + slot
        const int b = g >> 9, slot = g & (NM - 1);

        float a0[8] = {0,0,0,0,0,0,0,0};
        float a1[8] = {0,0,0,0,0,0,0,0};
        float a2[8] = {0,0,0,0,0,0,0,0};

        #pragma unroll
        for (int i = 0; i < NS; ++i) {
            const int s = __shfl(tokv, q * NS + i);
            const _Float16* p = Ch + (size_t)s * (3 * DIM) + l16 * 8;
            half8 v0 = *(const half8*)(p);
            half8 v1 = *(const half8*)(p + DIM);
            half8 v2 = *(const half8*)(p + 2 * DIM);
            #pragma unroll
            for (int j = 0; j < 8; ++j) {
                a0[j] = fmaf((float)v0[j], 1.0f, a0[j]);
                a1[j] = fmaf((float)v1[j], 1.0f, a1[j]);
                a2[j] = fmaf((float)v2[j], 1.0f, a2[j]);
            }
        }
        half8 h0, h1, h2;
        #pragma unroll
        for (int j = 0; j < 8; ++j) {
            h0[j] = (_Float16)a0[j]; h1[j] = (_Float16)a1[j]; h2[j] = (_Float16)a2[j];
        }
        const size_t o = ((size_t)b * SLOTS + slot) * DIM + l16 * 8;
        *(half8*)(msum + o)                 = h0;
        *(half8*)(msum + o + TABSTRIDE)     = h1;
        *(half8*)(msum + o + 2 * TABSTRIDE) = h2;
    }
}

// ---------------------------------------------------------------------------
// Fused hop chain: one 1024-thread block (16 waves) per batch element.
// (unchanged from previous round to isolate attribution)
// ---------------------------------------------------------------------------
__global__ __launch_bounds__(1024) void hops_fused(
    const _Float16* __restrict__ msum, float* __restrict__ out)
{
    const int b = blockIdx.x, t = threadIdx.x;
    const int rg = t >> 4, l16 = t & 15, wv = t >> 6, ln = t & 63;
    __shared__ float u_s[DIM];
    __shared__ float probs[SLOTS];
    __shared__ float part[64][DIM + 4];   // 33.8 KB; +4 pad -> 4*rg bank skew
    __shared__ float red[16];

    const _Float16* base = msum + (size_t)b * SLOTS * DIM;

    // ---- hop 0: u = (1/SLOTS) * sum of tab0 rows ----
    {
        float acc[8] = {0,0,0,0,0,0,0,0};
        #pragma unroll
        for (int m = rg; m < SLOTS; m += 64) {
            half8 v = *(const half8*)(base + (size_t)m * DIM + l16 * 8);
            #pragma unroll
            for (int j = 0; j < 8; ++j) acc[j] += (float)v[j];
        }
        #pragma unroll
        for (int j = 0; j < 8; ++j) part[rg][l16 * 8 + j] = acc[j];
        __syncthreads();
        if (t < DIM) {
            float s = 0.f;
            #pragma unroll
            for (int r = 0; r < 64; ++r) s += part[r][t];
            u_s[t] = s * (1.f / SLOTS);
        }
        __syncthreads();
    }

    // ---- hops 1..2 ----
    for (int hop = 1; hop < HOPS; ++hop) {
        const _Float16* mA = base + (size_t)(hop - 1) * TABSTRIDE;
        const _Float16* mC = base + (size_t)hop * TABSTRIDE;

        // scores: raw dot(mA[m], u) -> probs[m]
        #pragma unroll
        for (int m = rg; m < SLOTS; m += 64) {
            half8 v = *(const half8*)(mA + (size_t)m * DIM + l16 * 8);
            float d = 0.f;
            #pragma unroll
            for (int j = 0; j < 8; ++j) d = fmaf((float)v[j], u_s[l16 * 8 + j], d);
            d += __shfl_xor(d, 1); d += __shfl_xor(d, 2);
            d += __shfl_xor(d, 4); d += __shfl_xor(d, 8);
            if (l16 == 0) probs[m] = d;
        }
        __syncthreads();                 // raw scores visible

        // block softmax over SLOTS entries (t<SLOTS owns one)
        float s0 = (t < SLOTS) ? probs[t] : -INFINITY;
        float lmax = s0;
        #pragma unroll
        for (int off = 32; off > 0; off >>= 1) lmax = fmaxf(lmax, __shfl_xor(lmax, off));
        if (ln == 0) red[wv] = lmax;
        __syncthreads();                 // red(max) visible; raw reads all done
        lmax = red[0];
        #pragma unroll
        for (int r = 1; r < 16; ++r) lmax = fmaxf(lmax, red[r]);
        __syncthreads();                 // red free for reuse
        float e0 = (t < SLOTS) ? expf(s0 - lmax) : 0.f;
        if (t < SLOTS) probs[t] = e0;
        float lsum = e0;
        #pragma unroll
        for (int off = 32; off > 0; off >>= 1) lsum += __shfl_xor(lsum, off);
        if (ln == 0) red[wv] = lsum;
        __syncthreads();                 // exp probs + red(sum) visible
        float tot = red[0];
        #pragma unroll
        for (int r = 1; r < 16; ++r) tot += red[r];
        const float inv = 1.0f / tot;

        // weighted sum: u += inv * sum_m probs[m] * mC[m]
        float acc[8] = {0,0,0,0,0,0,0,0};
        #pragma unroll
        for (int m = rg; m < SLOTS; m += 64) {
            const float p = probs[m];
            half8 v = *(const half8*)(mC + (size_t)m * DIM + l16 * 8);
            #pragma unroll
            for (int j = 0; j < 8; ++j) acc[j] = fmaf(p, (float)v[j], acc[j]);
        }
        __syncthreads();
        #pragma unroll
        for (int j = 0; j < 8; ++j) part[rg][l16 * 8 + j] = acc[j];
        __syncthreads();
        if (t < DIM) {
            float s = 0.f;
            #pragma unroll
            for (int r = 0; r < 64; ++r) s += part[r][t];
            u_s[t] += s * inv;
        }
        __syncthreads();
    }

    if (t < DIM) out[b * DIM + t] = u_s[t];
}

extern "C" void kernel_launch(void* const* d_in, const int* in_sizes, int n_in,
                              void* d_out, int out_size, void* d_ws, size_t ws_size,
                              hipStream_t stream) {
    const float* C     = (const float*)d_in[0];   // [4][VOCAB][DIM] fp32
    const int*   story = (const int*)d_in[1];     // [32][512][6]
    const int*   kb    = (const int*)d_in[2];     // [32][128][64]
    float*       out   = (float*)d_out;           // [32][128] fp32

    _Float16* Ch   = (_Float16*)d_ws;             // [V][3][128] fp16 = 36.8 MiB
    _Float16* msum = Ch + CH_ELEMS;               // [3][NB][SLOTS][128] fp16 = 15 MiB

    convert_k<<<CONV_BLOCKS, 256, 0, stream>>>(C, Ch);
    gather_k<<<GATHER_BLOCKS, 256, 0, stream>>>(Ch, story, kb, msum);
    hops_fused<<<NB, 1024, 0, stream>>>(msum, out);
}